// Round 1
// baseline (12007.695 us; speedup 1.0000x reference)
//
#include <hip/hip_runtime.h>
#include <math.h>

#define N 64
#define NPAD 65
#define BLOCK 256
#define MAX_SWEEPS 12
#define EPSV 1e-5f
#define CONV_TOL2 1e-10f

// Batched symmetric eigensolve via parallel cyclic Jacobi (circle-method
// tournament ordering: 63 rounds x 32 disjoint pairs), then reconstruct
// Q diag(log(max(w,eps))) Q^T. One 256-thread block per 64x64 matrix.
// A and V staged in LDS with +1 padding (stride 65) so both row-phase
// (consecutive k) and col-phase (stride-65) accesses are conflict-free.
__global__ __launch_bounds__(BLOCK, 4) void spdlogmap_jacobi(
    const float* __restrict__ S, float* __restrict__ Out, int nmat) {
    __shared__ float As[N][NPAD];
    __shared__ float Vs[N][NPAD];
    __shared__ float cs[32];
    __shared__ float ss[32];
    __shared__ float red[BLOCK];
    __shared__ float lw[N];
    __shared__ int conv;

    const int tid = threadIdx.x;
    const int b = blockIdx.x;
    if (b >= nmat) return;
    const float* Sb = S + (size_t)b * (N * N);
    float* Ob = Out + (size_t)b * (N * N);

    // Load S, init V = I
    for (int e = tid; e < N * N; e += BLOCK) {
        const int i = e >> 6, j = e & 63;
        As[i][j] = Sb[e];
        Vs[i][j] = (i == j) ? 1.0f : 0.0f;
    }
    __syncthreads();

    for (int sweep = 0; sweep < MAX_SWEEPS; ++sweep) {
        for (int r = 0; r < 63; ++r) {
            // --- compute 32 disjoint rotations (Golub & Van Loan sym.schur2)
            if (tid < 32) {
                const int j = tid;
                const int a = (j == 0) ? 0 : (1 + (j - 1 + r) % 63);
                const int b2 = 1 + (62 - j + r) % 63;
                const int p = a < b2 ? a : b2;
                const int q = a < b2 ? b2 : a;
                const float apq = As[p][q];
                const float app = As[p][p];
                const float aqq = As[q][q];
                float c = 1.0f, s = 0.0f;
                if (fabsf(apq) > 1e-36f) {
                    const float tau = (aqq - app) / (2.0f * apq);
                    float t = 1.0f / (fabsf(tau) + sqrtf(1.0f + tau * tau));
                    t = (tau < 0.0f) ? -t : t;
                    c = rsqrtf(1.0f + t * t);
                    s = t * c;
                }
                cs[j] = c;
                ss[j] = s;
            }
            __syncthreads();
            // --- row phase: rows p,q <- J^T * rows p,q   (2048 items)
            #pragma unroll
            for (int ii = 0; ii < (32 * N) / BLOCK; ++ii) {
                const int it = tid + ii * BLOCK;
                const int j = it >> 6;
                const int k = it & 63;
                const int a = (j == 0) ? 0 : (1 + (j - 1 + r) % 63);
                const int b2 = 1 + (62 - j + r) % 63;
                const int p = a < b2 ? a : b2;
                const int q = a < b2 ? b2 : a;
                const float c = cs[j], s = ss[j];
                const float xp = As[p][k], xq = As[q][k];
                As[p][k] = c * xp - s * xq;
                As[q][k] = s * xp + c * xq;
            }
            __syncthreads();
            // --- col phase on A, plus eigenvector accumulation V <- V*J
            #pragma unroll
            for (int ii = 0; ii < (32 * N) / BLOCK; ++ii) {
                const int it = tid + ii * BLOCK;
                const int j = it >> 6;
                const int k = it & 63;
                const int a = (j == 0) ? 0 : (1 + (j - 1 + r) % 63);
                const int b2 = 1 + (62 - j + r) % 63;
                const int p = a < b2 ? a : b2;
                const int q = a < b2 ? b2 : a;
                const float c = cs[j], s = ss[j];
                const float xp = As[k][p], xq = As[k][q];
                As[k][p] = c * xp - s * xq;
                As[k][q] = s * xp + c * xq;
                const float vp = Vs[k][p], vq = Vs[k][q];
                Vs[k][p] = c * vp - s * vq;
                Vs[k][q] = s * vp + c * vq;
            }
            __syncthreads();
        }
        // --- convergence check: sum of squared off-diagonals
        float part = 0.0f;
        for (int e = tid; e < N * N; e += BLOCK) {
            const int i = e >> 6, j = e & 63;
            const float v = As[i][j];
            part += (i != j) ? v * v : 0.0f;
        }
        red[tid] = part;
        __syncthreads();
        if (tid < 64)
            red[tid] = red[tid] + red[tid + 64] + red[tid + 128] + red[tid + 192];
        __syncthreads();
        if (tid == 0) {
            float tot = 0.0f;
            #pragma unroll
            for (int i = 0; i < 64; ++i) tot += red[i];
            conv = (tot < CONV_TOL2) ? 1 : 0;
        }
        __syncthreads();
        if (conv) break;
    }

    // --- eigenvalues -> log(max(w, eps))
    if (tid < N) lw[tid] = logf(fmaxf(As[tid][tid], EPSV));
    __syncthreads();
    // As <- V * diag(lw)  (A no longer needed)
    for (int e = tid; e < N * N; e += BLOCK) {
        const int i = e >> 6, j = e & 63;
        As[i][j] = Vs[i][j] * lw[j];
    }
    __syncthreads();
    // Out = (V diag(lw)) V^T
    for (int e = tid; e < N * N; e += BLOCK) {
        const int i = e >> 6, j = e & 63;
        float acc = 0.0f;
        #pragma unroll 8
        for (int c = 0; c < N; ++c) acc += As[i][c] * Vs[j][c];
        Ob[e] = acc;
    }
}

extern "C" void kernel_launch(void* const* d_in, const int* in_sizes, int n_in,
                              void* d_out, int out_size, void* d_ws, size_t ws_size,
                              hipStream_t stream) {
    const float* S = (const float*)d_in[0];
    float* Out = (float*)d_out;
    const int nmat = in_sizes[0] / (N * N);
    spdlogmap_jacobi<<<nmat, BLOCK, 0, stream>>>(S, Out, nmat);
}

// Round 3
// 9369.330 us; speedup vs baseline: 1.2816x; 1.2816x over previous
//
#include <hip/hip_runtime.h>
#include <math.h>

#define EPSV 1e-5f
#define NSWEEP_MAX 12
#define CONV_TOL 1e-10f

// One 64-lane wave per 64x64 SPD matrix. Register-resident two-sided Jacobi,
// XOR pairing schedule: round m (1..63) rotates all pairs {i, i^m}.
// Lane l holds row l of A (a[s]) and column l of V (v[s]).
// Row phase    B = J^T A : ds_bpermute partner row (lane l^m), universal
//                          blend a = c*own + es*partner, es = -s_own.
// Stash        L[s][lane] = B[lane][s]  (lane-PRIVATE column of LDS — the
//                          only purpose of LDS here is runtime indexing of
//                          the own row; no cross-lane LDS traffic, so no
//                          barriers needed in the main loop).
// Col phase    A' = B J  : rB = L[s^m][lane] (own column), per-column
//                          coefficients via v_readlane (compile-time s).
// V update     V' = V J  : pure bpermute on v[].
// apq for round m comes from the PREVIOUS round's stash:
//   A_cur[l][x] = c_prev(x)*B_prev[l][x] + es_prev(x)*B_prev[l][x^m_prev]
// Diagonal kept exactly in register d: d' = d - t*apq.

__device__ __forceinline__ float bperm_f(int idx, float x) {
    return __int_as_float(__builtin_amdgcn_ds_bpermute(idx, __float_as_int(x)));
}
__device__ __forceinline__ float rdlane_f(float x, int l) {
    return __int_as_float(__builtin_amdgcn_readlane(__float_as_int(x), l));
}

__global__ __launch_bounds__(64, 2) void spdlog_wave(
    const float* __restrict__ S, float* __restrict__ Out, int nmat) {
    __shared__ float L[64][64];  // 16 KB
    const int lane = threadIdx.x;
    const int b = blockIdx.x;
    if (b >= nmat) return;
    const float* Sb = S + (size_t)b * 4096;
    float* Ob = Out + (size_t)b * 4096;

    // ---- load A into LDS (coalesced float4), L[i][j] = A[i][j]
    #pragma unroll
    for (int k4 = 0; k4 < 16; ++k4) {
        float4 t4 = *(const float4*)(Sb + k4 * 256 + lane * 4);
        const int i = k4 * 4 + (lane >> 4);
        const int j = (lane & 15) * 4;
        *(float4*)&L[i][j] = t4;
    }
    __syncthreads();

    float a[64], v[64];
    #pragma unroll 64
    for (int s = 0; s < 64; ++s) a[s] = L[s][lane];  // A symmetric: row lane
    #pragma unroll 64
    for (int s = 0; s < 64; ++s) v[s] = (s == lane) ? 1.0f : 0.0f;
    float d = L[lane][lane];

    float cprev = 1.0f, eprev = 0.0f;
    int mprev = 0;
    const int lane4 = lane << 2;
    float off_prev = 1e30f;

    #pragma unroll 1
    for (int sweep = 0; sweep < NSWEEP_MAX; ++sweep) {
        #pragma unroll 1
        for (int m = 1; m < 64; ++m) {
            const int pidx = lane4 ^ (m << 2);
            const int xl = lane ^ m;
            // ---- apq = A_cur[l][l^m] from previous round's stash
            const float r1 = L[xl][lane];
            const float r2 = L[xl ^ mprev][lane];
            const float ccx = bperm_f(pidx, cprev);
            const float eex = bperm_f(pidx, eprev);
            const float apq = fmaf(ccx, r1, eex * r2);
            const float pd = bperm_f(pidx, d);
            // ---- rotation (pair computes same c, opposite s)
            const float tau = (pd - d) * __builtin_amdgcn_rcpf(2.0f * apq);
            const float sq = __builtin_amdgcn_sqrtf(fmaf(tau, tau, 1.0f));
            float tt = __builtin_amdgcn_rcpf(fabsf(tau) + sq);
            tt = copysignf(tt, tau);
            float cc = __builtin_amdgcn_rsqf(fmaf(tt, tt, 1.0f));
            float ss = tt * cc;
            const bool tiny = fabsf(apq) < 1e-30f;
            cc = tiny ? 1.0f : cc;
            ss = tiny ? 0.0f : ss;
            tt = tiny ? 0.0f : tt;
            const float es = -ss;
            d = fmaf(-tt, apq, d);
            // ---- row phase: B = J^T A
            #pragma unroll 64
            for (int s = 0; s < 64; ++s) {
                const float pr = bperm_f(pidx, a[s]);
                a[s] = fmaf(cc, a[s], es * pr);
            }
            // ---- stash own row into own LDS column (lane-private)
            #pragma unroll 64
            for (int s = 0; s < 64; ++s) L[s][lane] = a[s];
            // ---- V update: V' = V J (pure bpermute)
            #pragma unroll 64
            for (int s = 0; s < 64; ++s) {
                const float pv = bperm_f(pidx, v[s]);
                v[s] = fmaf(cc, v[s], es * pv);
            }
            // ---- col phase: A' = B J (own-column LDS reads, SGPR coeffs)
            #pragma unroll 64
            for (int s = 0; s < 64; ++s) {
                const float rB = L[s ^ m][lane];
                const float rc = rdlane_f(cc, s);
                const float re = rdlane_f(es, s);
                a[s] = fmaf(rc, a[s], re * rB);
            }
            cprev = cc;
            eprev = es;
            mprev = m;
        }
        // ---- convergence: off-diagonal Frobenius^2 (diagonal slot masked)
        float off = 0.0f;
        #pragma unroll 64
        for (int s = 0; s < 64; ++s) {
            const float x = (s == lane) ? 0.0f : a[s];
            off = fmaf(x, x, off);
        }
        off += __shfl_xor(off, 1);
        off += __shfl_xor(off, 2);
        off += __shfl_xor(off, 4);
        off += __shfl_xor(off, 8);
        off += __shfl_xor(off, 16);
        off += __shfl_xor(off, 32);
        if (off < CONV_TOL) break;                           // converged
        if (sweep >= 3 && off > 0.25f * off_prev) break;     // rounding floor
        off_prev = off;
    }

    const float lw = logf(fmaxf(d, EPSV));

    // ---- reconstruction: O = V diag(lw) V^T
    #pragma unroll 64
    for (int s = 0; s < 64; ++s) L[s][lane] = v[s];  // L[s][l] = V[s][l]
    __syncthreads();
    float uw[64];
    {
        const float4* rowp = (const float4*)&L[lane][0];
        #pragma unroll 16
        for (int g = 0; g < 16; ++g) {
            const float4 q = rowp[g];
            uw[4 * g + 0] = q.x;
            uw[4 * g + 1] = q.y;
            uw[4 * g + 2] = q.z;
            uw[4 * g + 3] = q.w;
        }
    }
    #pragma unroll 64
    for (int c = 0; c < 64; ++c) uw[c] *= rdlane_f(lw, c);
    #pragma unroll 2
    for (int i = 0; i < 64; ++i) {
        const float4* Vrow = (const float4*)&L[i][0];  // wave-uniform: bcast
        float acc = 0.0f;
        #pragma unroll 16
        for (int g = 0; g < 16; ++g) {
            const float4 q = Vrow[g];
            acc = fmaf(q.x, uw[4 * g + 0], acc);
            acc = fmaf(q.y, uw[4 * g + 1], acc);
            acc = fmaf(q.z, uw[4 * g + 2], acc);
            acc = fmaf(q.w, uw[4 * g + 3], acc);
        }
        Ob[i * 64 + lane] = acc;
    }
}

extern "C" void kernel_launch(void* const* d_in, const int* in_sizes, int n_in,
                              void* d_out, int out_size, void* d_ws, size_t ws_size,
                              hipStream_t stream) {
    const float* S = (const float*)d_in[0];
    float* Out = (float*)d_out;
    const int nmat = in_sizes[0] / 4096;
    spdlog_wave<<<nmat, 64, 0, stream>>>(S, Out, nmat);
}

// Round 5
// 4400.163 us; speedup vs baseline: 2.7289x; 2.1293x over previous
//
#include <hip/hip_runtime.h>
#include <math.h>

#define NSWEEP_MAX 16
#define T2_TOL 1e-10f   // exit when max dpq^2/(dpp*dqq) below this
#define EPS2 1e-10f     // lambda clamp 1e-5 => lambda^2 clamp 1e-10

// One-sided Jacobi on G = S (SPD): orthogonalize columns; at convergence
// G = U diag(lambda), U = eigenvectors, lambda = column norms (since the
// SVD of an SPD S is Q Lambda Q^T). One 64-lane wave per matrix; lane l
// holds column l in 64 VGPRs. XOR pairing: round m rotates pairs {l, l^m}.
// Per round: 64 bpermute (partner column), lane-local dot for dpq, 128 fma.
// No LDS in the main loop.
//
// TIE-SAFE rotation: both lanes of a pair evaluate the rotation in the
// CANONICAL orientation (low-lane = "p"): tau = (d_hi - d_lo) * rcp(2*dpq).
// Operands and order are identical on both lanes -> tau/tt/cc/ss are
// bitwise identical; only the application sign differs:
//   es   = isLow ? -ss : +ss      (g' = cc*g_own + es*g_partner)
//   t_own= isLow ? +tt : -tt      (dpp' = dpp - t_own*dpq)
// This fixes the round-4 bug where tau==+0 on both lanes made both
// columns rotate with the same sign (pair collapse to parallel vectors).

__device__ __forceinline__ float bperm_f(int idx, float x) {
    return __int_as_float(__builtin_amdgcn_ds_bpermute(idx, __float_as_int(x)));
}
__device__ __forceinline__ float rdlane_f(float x, int l) {
    return __int_as_float(__builtin_amdgcn_readlane(__float_as_int(x), l));
}

__global__ __launch_bounds__(64, 3) void spdlog_onesided(
    const float* __restrict__ S, float* __restrict__ Out, int nmat) {
    __shared__ float X[64][64];  // 16 KB, reconstruction only
    const int lane = threadIdx.x;
    const int b = blockIdx.x;
    if (b >= nmat) return;
    const float* Sb = S + (size_t)b * 4096;
    float* Ob = Out + (size_t)b * 4096;

    // ---- load column `lane`: g[s] = S[s][lane] (coalesced across lanes)
    float g[64];
    #pragma unroll 64
    for (int s = 0; s < 64; ++s) g[s] = Sb[s * 64 + lane];

    float dpp = 0.0f;

    #pragma unroll 1
    for (int sweep = 0; sweep < NSWEEP_MAX; ++sweep) {
        // refresh Gram diagonal from actual column (kills drift)
        dpp = 0.0f;
        #pragma unroll 64
        for (int s = 0; s < 64; ++s) dpp = fmaf(g[s], g[s], dpp);

        float maxt2 = 0.0f;
        #pragma unroll 1
        for (int m = 1; m < 64; ++m) {
            const int xl = lane ^ m;
            const int idx = xl << 2;
            const bool isLow = lane < xl;
            // ---- fetch partner column, lane-local Gram cross term.
            // fma(a,b,c)==fma(b,a,c) bitwise -> dpq identical on both lanes.
            float pr[64];
            float dpq = 0.0f;
            #pragma unroll 64
            for (int s = 0; s < 64; ++s) {
                pr[s] = bperm_f(idx, g[s]);
                dpq = fmaf(g[s], pr[s], dpq);
            }
            const float pd = bperm_f(idx, dpp);
            const float d_lo = isLow ? dpp : pd;
            const float d_hi = isLow ? pd : dpp;
            // convergence metric (relative Gram off-diagonal, pre-rotation)
            const float t2 = dpq * dpq * __builtin_amdgcn_rcpf(dpp * pd);
            maxt2 = fmaxf(maxt2, t2);
            // ---- canonical rotation (identical bits on both lanes)
            const float tau = (d_hi - d_lo) * __builtin_amdgcn_rcpf(2.0f * dpq);
            const float sq = __builtin_amdgcn_sqrtf(fmaf(tau, tau, 1.0f));
            float tt = __builtin_amdgcn_rcpf(fabsf(tau) + sq);
            tt = copysignf(tt, tau);
            float cc = __builtin_amdgcn_rsqf(fmaf(tt, tt, 1.0f));
            float ss = tt * cc;
            const bool tiny = fabsf(dpq) < 1e-30f;
            cc = tiny ? 1.0f : cc;
            ss = tiny ? 0.0f : ss;
            tt = tiny ? 0.0f : tt;
            const float es = isLow ? -ss : ss;
            const float t_own = isLow ? tt : -tt;
            dpp = fmaf(-t_own, dpq, dpp);  // exact diagonal Gram update
            // ---- rotate own column (reuse fetched partner registers)
            #pragma unroll 64
            for (int s = 0; s < 64; ++s) g[s] = fmaf(cc, g[s], es * pr[s]);
        }
        // ---- wave max of maxt2
        maxt2 = fmaxf(maxt2, __shfl_xor(maxt2, 1));
        maxt2 = fmaxf(maxt2, __shfl_xor(maxt2, 2));
        maxt2 = fmaxf(maxt2, __shfl_xor(maxt2, 4));
        maxt2 = fmaxf(maxt2, __shfl_xor(maxt2, 8));
        maxt2 = fmaxf(maxt2, __shfl_xor(maxt2, 16));
        maxt2 = fmaxf(maxt2, __shfl_xor(maxt2, 32));
        if (maxt2 < T2_TOL) break;  // wave-uniform
    }

    // ---- fresh column norm^2 -> eigenvalue; clamp matches ref (on lambda)
    float dfin = 0.0f;
    #pragma unroll 64
    for (int s = 0; s < 64; ++s) dfin = fmaf(g[s], g[s], dfin);
    const float w = 0.5f * logf(fmaxf(dfin, EPS2));
    const float rs = __builtin_amdgcn_rsqf(fmaxf(dfin, 1e-20f));

    // ---- reconstruction: O = U diag(w) U^T, U columns = g*rs
    #pragma unroll 64
    for (int s = 0; s < 64; ++s) X[s][lane] = g[s] * rs;  // lane-private col
    __syncthreads();
    float uw[64];
    {
        const float4* rowp = (const float4*)&X[lane][0];  // own row of U
        #pragma unroll 16
        for (int gq = 0; gq < 16; ++gq) {
            const float4 q = rowp[gq];
            uw[4 * gq + 0] = q.x;
            uw[4 * gq + 1] = q.y;
            uw[4 * gq + 2] = q.z;
            uw[4 * gq + 3] = q.w;
        }
    }
    #pragma unroll 64
    for (int c = 0; c < 64; ++c) uw[c] *= rdlane_f(w, c);
    #pragma unroll 2
    for (int i = 0; i < 64; ++i) {
        const float4* Urow = (const float4*)&X[i][0];  // wave-uniform: bcast
        float acc = 0.0f;
        #pragma unroll 16
        for (int gq = 0; gq < 16; ++gq) {
            const float4 q = Urow[gq];
            acc = fmaf(q.x, uw[4 * gq + 0], acc);
            acc = fmaf(q.y, uw[4 * gq + 1], acc);
            acc = fmaf(q.z, uw[4 * gq + 2], acc);
            acc = fmaf(q.w, uw[4 * gq + 3], acc);
        }
        Ob[i * 64 + lane] = acc;
    }
}

extern "C" void kernel_launch(void* const* d_in, const int* in_sizes, int n_in,
                              void* d_out, int out_size, void* d_ws, size_t ws_size,
                              hipStream_t stream) {
    const float* S = (const float*)d_in[0];
    float* Out = (float*)d_out;
    const int nmat = in_sizes[0] / 4096;
    spdlog_onesided<<<nmat, 64, 0, stream>>>(S, Out, nmat);
}

// Round 6
// 4352.394 us; speedup vs baseline: 2.7589x; 1.0110x over previous
//
#include <hip/hip_runtime.h>
#include <math.h>

#define NSWEEP_MAX 16
#define T2_TOL 2e-9f    // exit when max dpq^2/(dpp*dqq) below this
#define EPS2 1e-10f     // lambda clamp 1e-5 => lambda^2 clamp 1e-10

// One-sided Jacobi on G = S (SPD): orthogonalize columns; at convergence
// G = U diag(lambda), U = eigenvectors, lambda = column norms. One 64-lane
// wave per matrix; lane l holds column l in 64 VGPRs. XOR pairing: round m
// rotates pairs {l, l^m}. Per round: ONE bpermute pass (64 instrs) fetching
// the partner column into pr[64] (kept LIVE across the rotation — this needs
// the relaxed __launch_bounds__(64,2) register budget; with (64,3) the
// compiler rematerialized the bpermutes, doubling LDS-pipe traffic), a
// lane-local dot for dpq, then a register-only rotate pass.
//
// TIE-SAFE rotation: both lanes of a pair evaluate the rotation in the
// CANONICAL orientation (low-lane = "p"): tau = (d_hi - d_lo) * rcp(2*dpq).
// Operands and order identical on both lanes -> bitwise-identical
// tau/tt/cc/ss; only the application sign differs:
//   es    = isLow ? -ss : +ss     (g' = cc*g_own + es*g_partner)
//   t_own = isLow ? +tt : -tt     (dpp' = dpp - t_own*dpq)

__device__ __forceinline__ float bperm_f(int idx, float x) {
    return __int_as_float(__builtin_amdgcn_ds_bpermute(idx, __float_as_int(x)));
}
__device__ __forceinline__ float rdlane_f(float x, int l) {
    return __int_as_float(__builtin_amdgcn_readlane(__float_as_int(x), l));
}

__global__ __launch_bounds__(64, 2) void spdlog_onesided(
    const float* __restrict__ S, float* __restrict__ Out, int nmat) {
    __shared__ float X[64][64];  // 16 KB, reconstruction only
    const int lane = threadIdx.x;
    const int b = blockIdx.x;
    if (b >= nmat) return;
    const float* Sb = S + (size_t)b * 4096;
    float* Ob = Out + (size_t)b * 4096;

    // ---- load column `lane`: g[s] = S[s][lane] (coalesced across lanes)
    float g[64];
    #pragma unroll 64
    for (int s = 0; s < 64; ++s) g[s] = Sb[s * 64 + lane];

    float dpp = 0.0f;

    #pragma unroll 1
    for (int sweep = 0; sweep < NSWEEP_MAX; ++sweep) {
        // refresh Gram diagonal from actual column (kills drift)
        dpp = 0.0f;
        #pragma unroll 64
        for (int s = 0; s < 64; ++s) dpp = fmaf(g[s], g[s], dpp);

        float maxt2 = 0.0f;
        #pragma unroll 1
        for (int m = 1; m < 64; ++m) {
            const int xl = lane ^ m;
            const int idx = xl << 2;
            const bool isLow = lane < xl;
            // ---- phase 1: fetch partner column (kept live), lane-local dot.
            // fma(a,b,c)==fma(b,a,c) bitwise -> dpq identical on both lanes.
            float pr[64];
            float dpq = 0.0f;
            #pragma unroll 64
            for (int s = 0; s < 64; ++s) {
                pr[s] = bperm_f(idx, g[s]);
                dpq = fmaf(g[s], pr[s], dpq);
            }
            const float pd = bperm_f(idx, dpp);
            const float d_lo = isLow ? dpp : pd;
            const float d_hi = isLow ? pd : dpp;
            // convergence metric (relative Gram off-diagonal, pre-rotation)
            const float t2 = dpq * dpq * __builtin_amdgcn_rcpf(dpp * pd);
            maxt2 = fmaxf(maxt2, t2);
            // ---- canonical rotation (identical bits on both lanes)
            const float tau = (d_hi - d_lo) * __builtin_amdgcn_rcpf(2.0f * dpq);
            const float sq = __builtin_amdgcn_sqrtf(fmaf(tau, tau, 1.0f));
            float tt = __builtin_amdgcn_rcpf(fabsf(tau) + sq);
            tt = copysignf(tt, tau);
            float cc = __builtin_amdgcn_rsqf(fmaf(tt, tt, 1.0f));
            float ss = tt * cc;
            const bool tiny = fabsf(dpq) < 1e-30f;
            cc = tiny ? 1.0f : cc;
            ss = tiny ? 0.0f : ss;
            tt = tiny ? 0.0f : tt;
            const float es = isLow ? -ss : ss;
            const float t_own = isLow ? tt : -tt;
            dpp = fmaf(-t_own, dpq, dpp);  // exact diagonal Gram update
            // ---- phase 2: register-only rotate (reuses live pr[])
            #pragma unroll 64
            for (int s = 0; s < 64; ++s) g[s] = fmaf(cc, g[s], es * pr[s]);
        }
        // ---- wave max of maxt2
        maxt2 = fmaxf(maxt2, __shfl_xor(maxt2, 1));
        maxt2 = fmaxf(maxt2, __shfl_xor(maxt2, 2));
        maxt2 = fmaxf(maxt2, __shfl_xor(maxt2, 4));
        maxt2 = fmaxf(maxt2, __shfl_xor(maxt2, 8));
        maxt2 = fmaxf(maxt2, __shfl_xor(maxt2, 16));
        maxt2 = fmaxf(maxt2, __shfl_xor(maxt2, 32));
        if (maxt2 < T2_TOL) break;  // wave-uniform
    }

    // ---- fresh column norm^2 -> eigenvalue; clamp matches ref (on lambda)
    float dfin = 0.0f;
    #pragma unroll 64
    for (int s = 0; s < 64; ++s) dfin = fmaf(g[s], g[s], dfin);
    const float w = 0.5f * logf(fmaxf(dfin, EPS2));
    const float rs = __builtin_amdgcn_rsqf(fmaxf(dfin, 1e-20f));

    // ---- reconstruction: O = U diag(w) U^T, U columns = g*rs
    #pragma unroll 64
    for (int s = 0; s < 64; ++s) X[s][lane] = g[s] * rs;  // lane-private col
    __syncthreads();
    float uw[64];
    {
        const float4* rowp = (const float4*)&X[lane][0];  // own row of U
        #pragma unroll 16
        for (int gq = 0; gq < 16; ++gq) {
            const float4 q = rowp[gq];
            uw[4 * gq + 0] = q.x;
            uw[4 * gq + 1] = q.y;
            uw[4 * gq + 2] = q.z;
            uw[4 * gq + 3] = q.w;
        }
    }
    #pragma unroll 64
    for (int c = 0; c < 64; ++c) uw[c] *= rdlane_f(w, c);
    #pragma unroll 2
    for (int i = 0; i < 64; ++i) {
        const float4* Urow = (const float4*)&X[i][0];  // wave-uniform: bcast
        float acc = 0.0f;
        #pragma unroll 16
        for (int gq = 0; gq < 16; ++gq) {
            const float4 q = Urow[gq];
            acc = fmaf(q.x, uw[4 * gq + 0], acc);
            acc = fmaf(q.y, uw[4 * gq + 1], acc);
            acc = fmaf(q.z, uw[4 * gq + 2], acc);
            acc = fmaf(q.w, uw[4 * gq + 3], acc);
        }
        Ob[i * 64 + lane] = acc;
    }
}

extern "C" void kernel_launch(void* const* d_in, const int* in_sizes, int n_in,
                              void* d_out, int out_size, void* d_ws, size_t ws_size,
                              hipStream_t stream) {
    const float* S = (const float*)d_in[0];
    float* Out = (float*)d_out;
    const int nmat = in_sizes[0] / 4096;
    spdlog_onesided<<<nmat, 64, 0, stream>>>(S, Out, nmat);
}